// Round 9
// baseline (129.038 us; speedup 1.0000x reference)
//
#include <hip/hip_runtime.h>
#include <math.h>

// AFM forward: out[b] = linear(b) + softmax-weighted pair-interaction projection.
// B=4096, F=26, d=64, P=325 pairs, af=64.
//
// R9: single-dispatch + cross-row pipelining. R8 post-mortem: per-SIMD VALU
// issue ~8% -- waves are ~90% stalled regardless of inner-loop shape; the
// invariant costs are the serialized prep dispatch, the per-wave prologue,
// and each wave eating the emb-gather latency cold. Changes:
//  - prep_kernel deleted: W1 frags loaded direct from global f32 (L2-hot
//    16 KB) with in-register cvt; pair (i,j) via closed-form triangular
//    decode i = floor((51 - sqrt(2601-8p))/2) (exact in f32 for p < 325).
//  - 2 rows per wave (2048 waves, 512 blocks): prologue amortized 2x, and
//    row-1's gather/stage issues while row-0's MFMA loop computes
//    (double-buffered per-wave LDS) -- gather latency hidden.
// Fused plain-exp softmax loop unchanged from R8.

#define NF 26
#define NP 325
#define NMT 21           // 21 m-tiles of 16 pairs (336; pads contribute e=0)
#define ED 64
#define AF 64
#define NDENSE 13
#define WPB 4            // waves per block
#define BLOCK (WPB * 64)
#define RPW 2            // rows per wave
#define ESTRIDE 72       // f16 elems per emb row (144 B, 16B-aligned)
#define EBYTES (ESTRIDE * 2)

typedef __attribute__((ext_vector_type(8))) _Float16 half8;
typedef __attribute__((ext_vector_type(4))) float f32x4;

__device__ __forceinline__ void wsync() {
    // wave-local producer->consumer ordering through LDS (verified R3-R8).
    __builtin_amdgcn_fence(__ATOMIC_ACQ_REL, "workgroup");
    __builtin_amdgcn_wave_barrier();
}

__global__ __launch_bounds__(BLOCK, 4)   // VGPR cap 128 (R4 lesson: never cap below live set)
void afm_kernel(const int*   __restrict__ sparse,   // [B,26]
                const float* __restrict__ dense,    // [B,13]
                const float* __restrict__ etab,     // [V,64]
                const float* __restrict__ ltab,     // [V]
                const float* __restrict__ wdense,   // [13]
                const float* __restrict__ bias,     // [1]
                const float* __restrict__ W1,       // [64,64] (d-major)
                const float* __restrict__ b1,       // [64]
                const float* __restrict__ w2,       // [64]
                const float* __restrict__ proj,     // [64]
                float*       __restrict__ out,      // [B]
                int B)
{
    const int t    = threadIdx.x;
    const int wave = t >> 6;
    const int lane = t & 63;
    const int qd   = lane >> 4;     // quad 0..3
    const int ln   = lane & 15;

    const int g  = blockIdx.x * WPB + wave;
    const int r0 = g * RPW;
    if (r0 >= B) return;                     // safe: no block barriers
    const int r1 = r0 + 1;

    __shared__ alignas(16) _Float16 emb_all[WPB][RPW][NF][ESTRIDE];  // 29952 B
    const char* __restrict__ ebase0 = (const char*)&emb_all[wave][0][0][0];

    // ---- W1 A-operand fragments, direct from global f32 (L2-hot 16 KB):
    //      bfr[nt][kh][j] = W1[k = kh*32+qd*8+j][af = nt*16+ln] ----
    half8 bfr[4][2];
    #pragma unroll
    for (int nt = 0; nt < 4; ++nt)
        #pragma unroll
        for (int kh = 0; kh < 2; ++kh) {
            const float* wp = W1 + (kh * 32 + qd * 8) * AF + nt * 16 + ln;
            half8 h;
            #pragma unroll
            for (int j = 0; j < 8; ++j) h[j] = (_Float16)wp[j * AF];
            bfr[nt][kh] = h;
        }

    // b1/w2 for af = nt*16 + qd*4 + rr  (C-row mapping)
    float4 b1v4[4], w2v4[4];
    #pragma unroll
    for (int nt = 0; nt < 4; ++nt) {
        b1v4[nt] = *(const float4*)(b1 + nt * 16 + qd * 4);
        w2v4[nt] = *(const float4*)(w2 + nt * 16 + qd * 4);
    }

    // ---- stage row r0 into buf0; linear part for both rows (overlaps) ----
    const int* __restrict__ srow0 = sparse + r0 * NF;
    const int* __restrict__ srow1 = sparse + r1 * NF;
    for (int task = lane; task < NF * 8; task += 64) {
        int f = task >> 3, c = task & 7;
        const float* src = etab + (size_t)srow0[f] * ED + c * 8;
        float4 v0 = *(const float4*)(src);
        float4 v1 = *(const float4*)(src + 4);
        half8 h = { (_Float16)v0.x, (_Float16)v0.y, (_Float16)v0.z, (_Float16)v0.w,
                    (_Float16)v1.x, (_Float16)v1.y, (_Float16)v1.z, (_Float16)v1.w };
        *(half8*)(&emb_all[wave][0][f][c * 8]) = h;
    }

    float lin0 = 0.f, lin1 = 0.f;
    if (lane < NF) {
        lin0 = ltab[srow0[lane]];
        if (r1 < B) lin1 = ltab[srow1[lane]];
    } else if (lane >= 32 && lane < 32 + NDENSE) {
        int k = lane - 32;
        lin0 = dense[r0 * NDENSE + k] * wdense[k];
        if (r1 < B) lin1 = dense[r1 * NDENSE + k] * wdense[k];
    }
    #pragma unroll
    for (int off = 32; off >= 1; off >>= 1) {
        lin0 += __shfl_xor(lin0, off, 64);
        lin1 += __shfl_xor(lin1, off, 64);
    }
    const float bb = bias[0];
    lin0 += bb; lin1 += bb;

    wsync();   // buf0 visible

    // ---- stage row r1 into buf1 NOW: its global-load + ds_write latency
    //      overlaps row-0's compute below. No sync needed until row-1 use. ----
    if (r1 < B) {
        for (int task = lane; task < NF * 8; task += 64) {
            int f = task >> 3, c = task & 7;
            const float* src = etab + (size_t)srow1[f] * ED + c * 8;
            float4 v0 = *(const float4*)(src);
            float4 v1 = *(const float4*)(src + 4);
            half8 h = { (_Float16)v0.x, (_Float16)v0.y, (_Float16)v0.z, (_Float16)v0.w,
                        (_Float16)v1.x, (_Float16)v1.y, (_Float16)v1.z, (_Float16)v1.w };
            *(half8*)(&emb_all[wave][1][f][c * 8]) = h;
        }
    }

    const int qo0 = qd * 16;        // byte offsets within an emb row
    const int qo1 = 64 + qd * 16;

    #pragma unroll 1
    for (int rr = 0; rr < RPW; ++rr) {
        const int r = r0 + rr;
        if (r >= B) break;
        if (rr) wsync();            // buf1 visible for the second pass
        const char* __restrict__ ebase = ebase0 + rr * (NF * EBYTES);

        // ---- fused loop: logits via operand-swapped MFMA + plain-exp
        //      accumulation. Loop-carried: l, acc0, acc1 only (R8). ----
        float l = 0.f;
        half8 acc0 = { (_Float16)0.f, (_Float16)0.f, (_Float16)0.f, (_Float16)0.f,
                       (_Float16)0.f, (_Float16)0.f, (_Float16)0.f, (_Float16)0.f };
        half8 acc1 = acc0;

        #pragma unroll
        for (int mt = 0; mt < NMT; ++mt) {
            const int p  = mt * 16 + ln;
            const int pc = (p < NP) ? p : 0;            // pad-safe decode input
            // closed-form triangular decode (exact in f32 for pc < 325)
            const float sq = sqrtf((float)(2601 - 8 * pc));
            const int fi = (int)((51.0f - sq) * 0.5f);
            const int fj = fi + 1 + pc - ((fi * (51 - fi)) >> 1);
            const int oi = fi * EBYTES, oj = fj * EBYTES;

            half8 ei0 = *(const half8*)(ebase + oi + qo0);
            half8 ei1 = *(const half8*)(ebase + oi + qo1);
            half8 ej0 = *(const half8*)(ebase + oj + qo0);
            half8 ej1 = *(const half8*)(ebase + oj + qo1);
            half8 x0 = ei0 * ej0;                       // pair product, in regs
            half8 x1 = ei1 * ej1;

            // logits: D[m=af][n=pair=ln]; C rows = qd*4+reg = af within nt*16
            float lgA = 0.f, lgB = 0.f;
            #pragma unroll
            for (int nt = 0; nt < 4; ++nt) {
                f32x4 acc = { b1v4[nt].x, b1v4[nt].y, b1v4[nt].z, b1v4[nt].w };
                acc = __builtin_amdgcn_mfma_f32_16x16x32_f16(bfr[nt][0], x0, acc, 0, 0, 0);
                acc = __builtin_amdgcn_mfma_f32_16x16x32_f16(bfr[nt][1], x1, acc, 0, 0, 0);
                float s0 = fmaf(fmaxf(acc[0], 0.f), w2v4[nt].x,
                                fmaxf(acc[1], 0.f) * w2v4[nt].y);
                float s1 = fmaf(fmaxf(acc[2], 0.f), w2v4[nt].z,
                                fmaxf(acc[3], 0.f) * w2v4[nt].w);
                if (nt & 1) lgB += s0 + s1; else lgA += s0 + s1;   // 2 indep chains
            }
            float lg = lgA + lgB;
            lg += __shfl_xor(lg, 16, 64);
            lg += __shfl_xor(lg, 32, 64);

            // plain exp (logits bounded ~|1|); pads contribute 0
            float e = (p < NP) ? __expf(lg) : 0.f;
            l += e;
            const _Float16 eh = (_Float16)e;
            half8 e8 = { eh, eh, eh, eh, eh, eh, eh, eh };
            acc0 += x0 * e8;                            // v_pk_fma_f16
            acc1 += x1 * e8;
        }

        // ---- merge: denominator (sum over ln bits; replicated across qd) ----
        float lsum = l;
        #pragma unroll
        for (int off = 1; off <= 8; off <<= 1) lsum += __shfl_xor(lsum, off, 64);

        // numerator: proj-dot in-lane (dims qd*8..+7 and 32+qd*8..+7)
        float4 pa = *(const float4*)(proj + qd * 8);
        float4 pb = *(const float4*)(proj + qd * 8 + 4);
        float4 pc4 = *(const float4*)(proj + 32 + qd * 8);
        float4 pd = *(const float4*)(proj + 32 + qd * 8 + 4);
        float rrv = (float)acc0[0] * pa.x + (float)acc0[1] * pa.y
                  + (float)acc0[2] * pa.z + (float)acc0[3] * pa.w
                  + (float)acc0[4] * pb.x + (float)acc0[5] * pb.y
                  + (float)acc0[6] * pb.z + (float)acc0[7] * pb.w
                  + (float)acc1[0] * pc4.x + (float)acc1[1] * pc4.y
                  + (float)acc1[2] * pc4.z + (float)acc1[3] * pc4.w
                  + (float)acc1[4] * pd.x + (float)acc1[5] * pd.y
                  + (float)acc1[6] * pd.z + (float)acc1[7] * pd.w;
        #pragma unroll
        for (int off = 1; off <= 32; off <<= 1) rrv += __shfl_xor(rrv, off, 64);

        if (lane == 0) out[r] = ((rr == 0) ? lin0 : lin1) + rrv / lsum;
    }
}

extern "C" void kernel_launch(void* const* d_in, const int* in_sizes, int n_in,
                              void* d_out, int out_size, void* d_ws, size_t ws_size,
                              hipStream_t stream) {
    const int*   sparse = (const int*)  d_in[0];
    const float* dense  = (const float*)d_in[1];
    const float* etab   = (const float*)d_in[2];
    const float* ltab   = (const float*)d_in[3];
    const float* wdense = (const float*)d_in[4];
    const float* bias   = (const float*)d_in[5];
    const float* W1     = (const float*)d_in[6];
    const float* b1     = (const float*)d_in[7];
    const float* w2     = (const float*)d_in[8];
    const float* proj   = (const float*)d_in[9];
    float* outp = (float*)d_out;

    const int B = in_sizes[0] / NF;
    const int rows_per_block = WPB * RPW;
    const int grid = (B + rows_per_block - 1) / rows_per_block;   // 512 @ B=4096

    afm_kernel<<<dim3(grid), dim3(BLOCK), 0, stream>>>(
        sparse, dense, etab, ltab, wdense, bias, W1, b1, w2, proj, outp, B);
    (void)n_in; (void)out_size; (void)ws_size; (void)d_ws;
}

// Round 10
// 120.098 us; speedup vs baseline: 1.0744x; 1.0744x over previous
//
#include <hip/hip_runtime.h>
#include <math.h>

// AFM forward: out[b] = linear(b) + softmax-weighted pair-interaction projection.
// B=4096, F=26, d=64, P=325 pairs, af=64.
//
// R10: fused plain-exp loop (R8) x 2 waves per row (R5) with end-only merge.
// R9 post-mortem: W1-direct strided loads spilled (WRITE 17 MB) -- prep_kernel
// restored; closed-form pair decode kept (verified, kills ptab loads).
// R5/R6's 2-wave split gained nothing because 3 block barriers serialized the
// phases; here each wave runs the whole fused pipeline independently on its
// half of the m-tiles (wave w: mt = w, w+2, ...) and the ONLY cross-wave
// coupling is a 4-float LDS merge + one __syncthreads at the end.
// Wave lifetime ~halves; TLP doubles to 8192 waves.

#define NF 26
#define NP 325
#define NMT 21           // m-tiles of 16 pairs (336; pads contribute e=0)
#define ED 64
#define AF 64
#define NDENSE 13
#define BLOCK 128        // 2 waves, one row per block
#define ESTRIDE 72       // f16 elems per emb row (144 B: 16B-aligned, b128-clean)
#define EBYTES (ESTRIDE * 2)

typedef __attribute__((ext_vector_type(8))) _Float16 half8;
typedef __attribute__((ext_vector_type(4))) float f32x4;

__global__ void prep_kernel(const float* __restrict__ W1,
                            _Float16* __restrict__ w1t)   // [64][64] = W1^T, f16
{
    int t = threadIdx.x;
    for (int idx = t; idx < ED * AF; idx += 256) {
        int d = idx >> 6, a = idx & 63;       // W1 is [d][a]
        w1t[a * ED + d] = (_Float16)W1[idx];
    }
}

__global__ __launch_bounds__(BLOCK, 4)   // VGPR cap 128 (R4/R9 lesson: never cap below live set)
void afm_kernel(const int*   __restrict__ sparse,   // [B,26]
                const float* __restrict__ dense,    // [B,13]
                const float* __restrict__ etab,     // [V,64]
                const float* __restrict__ ltab,     // [V]
                const float* __restrict__ wdense,   // [13]
                const float* __restrict__ bias,     // [1]
                const float* __restrict__ b1,       // [64]
                const float* __restrict__ w2,       // [64]
                const float* __restrict__ proj,     // [64]
                const _Float16* __restrict__ w1t,   // [64][64] f16 (a-major)
                float*       __restrict__ out)      // [B]
{
    const int t    = threadIdx.x;
    const int wave = t >> 6;
    const int lane = t & 63;
    const int qd   = lane >> 4;     // quad 0..3
    const int ln   = lane & 15;
    const int r    = blockIdx.x;    // this block's batch row

    __shared__ alignas(16) _Float16 emb[NF][ESTRIDE];   // 3744 B
    __shared__ float merge[2][2];                       // {rrv, lsum} per wave
    const char* __restrict__ ebase = (const char*)emb;

    // ---- W1^T A-operand fragments (L2-hot 8 KB, proven no-spill layout):
    //      bfr[nt][kh] = w1t[af = nt*16+ln][k = kh*32 + qd*8 + j] ----
    half8 bfr[4][2];
    #pragma unroll
    for (int nt = 0; nt < 4; ++nt)
        #pragma unroll
        for (int kh = 0; kh < 2; ++kh)
            bfr[nt][kh] = *(const half8*)(w1t + (nt * 16 + ln) * ED + kh * 32 + qd * 8);

    // b1/w2 for af = nt*16 + qd*4 + rr  (C-row mapping)
    float4 b1v4[4], w2v4[4];
    #pragma unroll
    for (int nt = 0; nt < 4; ++nt) {
        b1v4[nt] = *(const float4*)(b1 + nt * 16 + qd * 4);
        w2v4[nt] = *(const float4*)(w2 + nt * 16 + qd * 4);
    }

    // ---- stage this row's 26 embeddings into LDS as f16 (both waves) ----
    const int* __restrict__ srow = sparse + r * NF;
    for (int task = t; task < NF * 8; task += BLOCK) {
        int f = task >> 3, c = task & 7;                 // 8-half chunk
        const float* src = etab + (size_t)srow[f] * ED + c * 8;
        float4 v0 = *(const float4*)(src);
        float4 v1 = *(const float4*)(src + 4);
        half8 h = { (_Float16)v0.x, (_Float16)v0.y, (_Float16)v0.z, (_Float16)v0.w,
                    (_Float16)v1.x, (_Float16)v1.y, (_Float16)v1.z, (_Float16)v1.w };
        *(half8*)(&emb[f][c * 8]) = h;
    }

    // ---- linear part (wave 0 registers; lands on t==0 which writes out) ----
    float lin = 0.f;
    if (wave == 0) {
        if (lane < NF) {
            lin = ltab[srow[lane]];
        } else if (lane >= 32 && lane < 32 + NDENSE) {
            int k = lane - 32;
            lin = dense[r * NDENSE + k] * wdense[k];
        }
        #pragma unroll
        for (int off = 32; off >= 1; off >>= 1) lin += __shfl_xor(lin, off, 64);
        lin += bias[0];
    }

    __syncthreads();   // emb visible (couples only 2 waves)

    // ---- fused loop: this wave's m-tiles (mt = wave, wave+2, ...).
    //      Loop-carried state: l, acc0, acc1 only (R8 plain-exp scheme;
    //      logits bounded ~|1| -> no max subtraction needed). ----
    const int qo0 = qd * 16;            // byte offsets within an emb row
    const int qo1 = 64 + qd * 16;

    float l = 0.f;
    half8 acc0 = { (_Float16)0.f, (_Float16)0.f, (_Float16)0.f, (_Float16)0.f,
                   (_Float16)0.f, (_Float16)0.f, (_Float16)0.f, (_Float16)0.f };
    half8 acc1 = acc0;

    #pragma unroll
    for (int k = 0; k < 11; ++k) {
        const int mt = 2 * k + wave;                // wave1's k=10 -> mt=21: dead iter, e=0
        const int p  = mt * 16 + ln;
        const int pc = (p < NP) ? p : 0;            // pad-safe decode input
        // closed-form triangular decode (exact in f32 for pc < 325; verified R9)
        const float sq = sqrtf((float)(2601 - 8 * pc));
        const int fi = (int)((51.0f - sq) * 0.5f);
        const int fj = fi + 1 + pc - ((fi * (51 - fi)) >> 1);
        const int oi = fi * EBYTES, oj = fj * EBYTES;

        half8 ei0 = *(const half8*)(ebase + oi + qo0);
        half8 ei1 = *(const half8*)(ebase + oi + qo1);
        half8 ej0 = *(const half8*)(ebase + oj + qo0);
        half8 ej1 = *(const half8*)(ebase + oj + qo1);
        half8 x0 = ei0 * ej0;                       // pair product, in registers
        half8 x1 = ei1 * ej1;

        // logits: D[m=af][n=pair=ln]; C rows = qd*4+reg = af within nt*16
        float lg = 0.f;
        #pragma unroll
        for (int nt = 0; nt < 4; ++nt) {
            f32x4 acc = { b1v4[nt].x, b1v4[nt].y, b1v4[nt].z, b1v4[nt].w };
            acc = __builtin_amdgcn_mfma_f32_16x16x32_f16(bfr[nt][0], x0, acc, 0, 0, 0);
            acc = __builtin_amdgcn_mfma_f32_16x16x32_f16(bfr[nt][1], x1, acc, 0, 0, 0);
            lg = fmaf(fmaxf(acc[0], 0.f), w2v4[nt].x, lg);
            lg = fmaf(fmaxf(acc[1], 0.f), w2v4[nt].y, lg);
            lg = fmaf(fmaxf(acc[2], 0.f), w2v4[nt].z, lg);
            lg = fmaf(fmaxf(acc[3], 0.f), w2v4[nt].w, lg);
        }
        // sum over the 4 qd groups -> full logit, replicated across qd
        lg += __shfl_xor(lg, 16, 64);
        lg += __shfl_xor(lg, 32, 64);

        float e = (p < NP) ? __expf(lg) : 0.f;      // pads (and mt=21) -> 0
        l += e;
        const _Float16 eh = (_Float16)e;
        half8 e8 = { eh, eh, eh, eh, eh, eh, eh, eh };
        acc0 += x0 * e8;                            // v_pk_fma_f16
        acc1 += x1 * e8;
    }

    // ---- per-wave reduction to 2 scalars ----
    float lsum = l;                                  // sum over ln bits
    #pragma unroll
    for (int off = 1; off <= 8; off <<= 1) lsum += __shfl_xor(lsum, off, 64);

    float4 pa = *(const float4*)(proj + qd * 8);
    float4 pb = *(const float4*)(proj + qd * 8 + 4);
    float4 pc4 = *(const float4*)(proj + 32 + qd * 8);
    float4 pd = *(const float4*)(proj + 32 + qd * 8 + 4);
    float rrv = (float)acc0[0] * pa.x + (float)acc0[1] * pa.y
              + (float)acc0[2] * pa.z + (float)acc0[3] * pa.w
              + (float)acc0[4] * pb.x + (float)acc0[5] * pb.y
              + (float)acc0[6] * pb.z + (float)acc0[7] * pb.w
              + (float)acc1[0] * pc4.x + (float)acc1[1] * pc4.y
              + (float)acc1[2] * pc4.z + (float)acc1[3] * pc4.w
              + (float)acc1[4] * pd.x + (float)acc1[5] * pd.y
              + (float)acc1[6] * pd.z + (float)acc1[7] * pd.w;
    #pragma unroll
    for (int off = 1; off <= 32; off <<= 1) rrv += __shfl_xor(rrv, off, 64);

    if (lane == 0) { merge[wave][0] = rrv; merge[wave][1] = lsum; }

    __syncthreads();   // the only post-stage cross-wave coupling

    if (t == 0)
        out[r] = lin + (merge[0][0] + merge[1][0]) / (merge[0][1] + merge[1][1]);
}

extern "C" void kernel_launch(void* const* d_in, const int* in_sizes, int n_in,
                              void* d_out, int out_size, void* d_ws, size_t ws_size,
                              hipStream_t stream) {
    const int*   sparse = (const int*)  d_in[0];
    const float* dense  = (const float*)d_in[1];
    const float* etab   = (const float*)d_in[2];
    const float* ltab   = (const float*)d_in[3];
    const float* wdense = (const float*)d_in[4];
    const float* bias   = (const float*)d_in[5];
    const float* W1     = (const float*)d_in[6];
    const float* b1     = (const float*)d_in[7];
    const float* w2     = (const float*)d_in[8];
    const float* proj   = (const float*)d_in[9];
    float* outp = (float*)d_out;

    _Float16* w1t = (_Float16*)d_ws;   // 8192 B

    const int B = in_sizes[0] / NF;

    prep_kernel<<<dim3(1), dim3(256), 0, stream>>>(W1, w1t);
    afm_kernel<<<dim3(B), dim3(BLOCK), 0, stream>>>(
        sparse, dense, etab, ltab, wdense, bias, b1, w2, proj, w1t, outp);
    (void)n_in; (void)out_size; (void)ws_size;
}